// Round 7
// baseline (21.932 us; speedup 1.0000x reference)
//
#include <hip/hip_runtime.h>
#include <math.h>

#define N_WAY 64
#define N_SUP 16
#define DIM   1024
#define N_QUERIES 4096
#define ROWS_PER_WAY 80
#define QT 16
#define GEMM_BLOCKS 256   // N_QUERIES / QT

typedef __attribute__((ext_vector_type(8))) short short8;
typedef __attribute__((ext_vector_type(4))) float f32x4;

// bf16 round-to-nearest-even
__device__ __forceinline__ unsigned short bf16_rne(float f) {
  unsigned u = __float_as_uint(f);
  return (unsigned short)((u + 0x7fffu + ((u >> 16) & 1u)) >> 16);
}

// Packed B-fragment layout (validated round 3): short8 index (kb*4+tile)*64+lane,
// lane = kgrp*16 + n15 holds way tile*16+n15, k = kb*32 + kgrp*8 + j.

// ---------------------------------------------------------------------------
// Kernel A: prototypes -> packed bf16 fragments + per-quarter pnorm partials.
// grid = 256 (4 blocks per way), block = 256. No atomics. Also zeroes d_out
// (plain store; end-of-dispatch release makes it visible to gemm's atomics).
// ---------------------------------------------------------------------------
__global__ __launch_bounds__(256) void proto_kernel(
    const float* __restrict__ x, unsigned short* __restrict__ phi,
    float* __restrict__ pnorm4, float* __restrict__ out) {
  const int way = blockIdx.x >> 2;
  const int cg  = blockIdx.x & 3;       // column quarter
  const int t   = threadIdx.x;
  const int lc  = t & 63;               // local f32x4 col
  const int sg  = t >> 6;               // support group (4 rows)
  const float4* x4 = (const float4*)x;
  const int base = way * ROWS_PER_WAY * (DIM / 4);
  const int col = cg * 64 + lc;         // f32x4 col 0..255

  if (blockIdx.x == 0 && t == 0) { out[0] = 0.f; out[1] = 0.f; }

  float4 a = make_float4(0.f, 0.f, 0.f, 0.f);
  #pragma unroll
  for (int r = 0; r < 4; ++r) {
    float4 v = x4[base + (sg * 4 + r) * (DIM / 4) + col];
    a.x += v.x; a.y += v.y; a.z += v.z; a.w += v.w;
  }
  __shared__ float4 pars[4][64];
  pars[sg][lc] = a;
  __syncthreads();

  if (t < 64) {
    float4 a0 = pars[0][t], a1 = pars[1][t], a2 = pars[2][t], a3 = pars[3][t];
    const float inv = 1.0f / 16.0f;
    float vals[4] = {(a0.x + a1.x + a2.x + a3.x) * inv,
                     (a0.y + a1.y + a2.y + a3.y) * inv,
                     (a0.z + a1.z + a2.z + a3.z) * inv,
                     (a0.w + a1.w + a2.w + a3.w) * inv};
    const int c   = cg * 64 + t;        // f32x4 col 0..255
    const int kb2 = c >> 3, kg2 = (c >> 1) & 3, j0 = (c & 1) * 4;
    const int tile = way >> 4;
    const int ln = kg2 * 16 + (way & 15);
    const int uidx = ((kb2 * 4 + tile) * 64 + ln) * 8 + j0;
    *(ushort4*)(phi + uidx) = make_ushort4(bf16_rne(vals[0]), bf16_rne(vals[1]),
                                           bf16_rne(vals[2]), bf16_rne(vals[3]));

    float pq = vals[0] * vals[0] + vals[1] * vals[1] +
               vals[2] * vals[2] + vals[3] * vals[3];
    #pragma unroll
    for (int off = 32; off > 0; off >>= 1) pq += __shfl_down(pq, off);
    if (t == 0) pnorm4[way * 4 + cg] = pq;   // plain store, no atomic
  }
}

// ---------------------------------------------------------------------------
// Kernel B: bf16 MFMA gemm + fused per-tile softmax. Tail: two device-scope
// atomicAdds straight into d_out (no finalize dispatch). grid = 256,
// block = 512; wave wv owns K-slice [wv*128, wv*128+128).
// ---------------------------------------------------------------------------
__global__ __launch_bounds__(512) void gemm_kernel(
    const float* __restrict__ x, const unsigned short* __restrict__ phi,
    const float* __restrict__ pnorm4, float* __restrict__ out) {
  __shared__ float Sp[8][16][68];   // per-wave partial tiles (padded)
  __shared__ float So[16][68];      // reduced logits
  __shared__ float pnL[64];

  const int tid  = threadIdx.x;
  const int wv   = tid >> 6;
  const int lane = tid & 63;
  const int lrow = lane & 15;
  const int kgrp = lane >> 4;
  const int qb   = blockIdx.x * QT;

  // ---- issue all B loads first (16 x 1KB coalesced), then A loads ----
  const short8* bhp = (const short8*)phi + lane;
  short8 bhv[4][4];
  #pragma unroll
  for (int s = 0; s < 4; ++s)
    #pragma unroll
    for (int t = 0; t < 4; ++t)
      bhv[s][t] = bhp[((wv * 4 + s) * 4 + t) * 64];

  const int qrow = (qb >> 6) * ROWS_PER_WAY + N_SUP + (qb & 63) + lrow;
  const float* arow = x + (size_t)qrow * DIM + kgrp * 8;
  f32x4 a0[4], a1[4];
  #pragma unroll
  for (int s = 0; s < 4; ++s) {
    a0[s] = *(const f32x4*)(arow + (wv * 4 + s) * 32);
    a1[s] = *(const f32x4*)(arow + (wv * 4 + s) * 32 + 4);
  }
  if (tid < 64)
    pnL[tid] = pnorm4[4 * tid] + pnorm4[4 * tid + 1] +
               pnorm4[4 * tid + 2] + pnorm4[4 * tid + 3];

  // ---- convert A to bf16 (RNE) ----
  short8 ah[4];
  #pragma unroll
  for (int s = 0; s < 4; ++s)
    #pragma unroll
    for (int j = 0; j < 4; ++j) {
      ah[s][j]     = (short)bf16_rne(a0[s][j]);
      ah[s][4 + j] = (short)bf16_rne(a1[s][j]);
    }

  // ---- 16 MFMAs ----
  f32x4 acc[4];
  #pragma unroll
  for (int t = 0; t < 4; ++t) acc[t] = (f32x4){0.f, 0.f, 0.f, 0.f};
  #pragma unroll
  for (int s = 0; s < 4; ++s)
    #pragma unroll
    for (int t = 0; t < 4; ++t)
      acc[t] = __builtin_amdgcn_mfma_f32_16x16x32_bf16(ah[s], bhv[s][t], acc[t], 0, 0, 0);

  // per-wave partials: C/D layout col(way)=lane&15, row(q)=kgrp*4+r (validated)
  #pragma unroll
  for (int t = 0; t < 4; ++t)
    #pragma unroll
    for (int r = 0; r < 4; ++r)
      Sp[wv][kgrp * 4 + r][t * 16 + lrow] = acc[t][r];
  __syncthreads();

  // reduce 8 K-slices, apply 2*dot - pnorm
  for (int i = tid; i < QT * N_WAY; i += 512) {
    int q = i >> 6, w = i & 63;
    float s = 0.f;
    #pragma unroll
    for (int v = 0; v < 8; ++v) s += Sp[v][q][w];
    So[q][w] = 2.f * s - pnL[w];
  }
  __syncthreads();

  // fused log-softmax + argmax: wave 0, 64 lanes = 16 q x 4 way-quarters
  if (tid < 64) {
    const int q = lane & 15;
    const int wq = lane >> 4;
    const int label = qb >> 6;
    float m = -INFINITY; int arg = 0;
    #pragma unroll
    for (int i = 0; i < 16; ++i) {
      int w = wq * 16 + i;
      float v = So[q][w];
      if (v > m) { m = v; arg = w; }
    }
    #pragma unroll
    for (int off = 16; off < 64; off <<= 1) {
      float om = __shfl_xor(m, off);
      int oa = __shfl_xor(arg, off);
      if (om > m || (om == m && oa < arg)) { m = om; arg = oa; }
    }
    float sum = 0.f;
    #pragma unroll
    for (int i = 0; i < 16; ++i) sum += expf(So[q][wq * 16 + i] - m);
    sum += __shfl_xor(sum, 16);
    sum += __shfl_xor(sum, 32);

    float lossq = 0.f, corr = 0.f;
    if (lane < 16) {
      lossq = m + logf(sum) - So[q][label];
      corr = (arg == label) ? 1.f : 0.f;
    }
    #pragma unroll
    for (int off = 8; off > 0; off >>= 1) {
      lossq += __shfl_down(lossq, off);
      corr  += __shfl_down(corr, off);
    }
    if (lane == 0) {   // device-scope atomics straight into d_out
      atomicAdd(&out[0], lossq * (1.0f / (float)N_QUERIES));
      atomicAdd(&out[1], corr * (100.0f / (float)N_QUERIES));
    }
  }
}

extern "C" void kernel_launch(void* const* d_in, const int* in_sizes, int n_in,
                              void* d_out, int out_size, void* d_ws, size_t ws_size,
                              hipStream_t stream) {
  (void)in_sizes; (void)n_in; (void)out_size; (void)ws_size;
  const float* x = (const float*)d_in[0];
  float* out = (float*)d_out;

  unsigned short* phi = (unsigned short*)d_ws;        // 64*1024 u16 packed
  float* pnorm4 = (float*)(phi + N_WAY * DIM);        // 256 f32

  hipLaunchKernelGGL(proto_kernel, dim3(256), dim3(256), 0, stream,
                     x, phi, pnorm4, out);
  hipLaunchKernelGGL(gemm_kernel, dim3(GEMM_BLOCKS), dim3(512), 0, stream,
                     x, phi, pnorm4, out);
}

// Round 8
// 20.340 us; speedup vs baseline: 1.0783x; 1.0783x over previous
//
#include <hip/hip_runtime.h>
#include <math.h>

#define N_WAY 64
#define N_SUP 16
#define DIM   1024
#define N_QUERIES 4096
#define ROWS_PER_WAY 80
#define QT 16
#define GEMM_BLOCKS 256   // N_QUERIES / QT

typedef __attribute__((ext_vector_type(8))) short short8;
typedef __attribute__((ext_vector_type(4))) float f32x4;

// bf16 round-to-nearest-even
__device__ __forceinline__ unsigned short bf16_rne(float f) {
  unsigned u = __float_as_uint(f);
  return (unsigned short)((u + 0x7fffu + ((u >> 16) & 1u)) >> 16);
}

// Packed B-fragment layout (validated round 3): short8 index (kb*4+tile)*64+lane,
// lane = kgrp*16 + n15 holds way tile*16+n15, k = kb*32 + kgrp*8 + j.

// ---------------------------------------------------------------------------
// Kernel A: prototypes -> packed bf16 fragments + per-quarter pnorm partials.
// grid = 256 (4 blocks per way), block = 256. No atomics. Zeroes the
// completion counter (visible to gemm via the node-boundary release).
// ---------------------------------------------------------------------------
__global__ __launch_bounds__(256) void proto_kernel(
    const float* __restrict__ x, unsigned short* __restrict__ phi,
    float* __restrict__ pnorm4, unsigned* __restrict__ ctr) {
  const int way = blockIdx.x >> 2;
  const int cg  = blockIdx.x & 3;       // column quarter
  const int t   = threadIdx.x;
  const int lc  = t & 63;               // local f32x4 col
  const int sg  = t >> 6;               // support group (4 rows)
  const float4* x4 = (const float4*)x;
  const int base = way * ROWS_PER_WAY * (DIM / 4);
  const int col = cg * 64 + lc;         // f32x4 col 0..255

  if (blockIdx.x == 0 && t == 0) *ctr = 0u;   // plain store, replay-safe

  float4 a = make_float4(0.f, 0.f, 0.f, 0.f);
  #pragma unroll
  for (int r = 0; r < 4; ++r) {
    float4 v = x4[base + (sg * 4 + r) * (DIM / 4) + col];
    a.x += v.x; a.y += v.y; a.z += v.z; a.w += v.w;
  }
  __shared__ float4 pars[4][64];
  pars[sg][lc] = a;
  __syncthreads();

  if (t < 64) {
    float4 a0 = pars[0][t], a1 = pars[1][t], a2 = pars[2][t], a3 = pars[3][t];
    const float inv = 1.0f / 16.0f;
    float vals[4] = {(a0.x + a1.x + a2.x + a3.x) * inv,
                     (a0.y + a1.y + a2.y + a3.y) * inv,
                     (a0.z + a1.z + a2.z + a3.z) * inv,
                     (a0.w + a1.w + a2.w + a3.w) * inv};
    const int c   = cg * 64 + t;        // f32x4 col 0..255
    const int kb2 = c >> 3, kg2 = (c >> 1) & 3, j0 = (c & 1) * 4;
    const int tile = way >> 4;
    const int ln = kg2 * 16 + (way & 15);
    const int uidx = ((kb2 * 4 + tile) * 64 + ln) * 8 + j0;
    *(ushort4*)(phi + uidx) = make_ushort4(bf16_rne(vals[0]), bf16_rne(vals[1]),
                                           bf16_rne(vals[2]), bf16_rne(vals[3]));

    float pq = vals[0] * vals[0] + vals[1] * vals[1] +
               vals[2] * vals[2] + vals[3] * vals[3];
    #pragma unroll
    for (int off = 32; off > 0; off >>= 1) pq += __shfl_down(pq, off);
    if (t == 0) pnorm4[way * 4 + cg] = pq;   // plain store, no atomic
  }
}

// ---------------------------------------------------------------------------
// Kernel B: bf16 MFMA gemm + fused per-tile softmax + last-block finalize.
// Tail: 2 relaxed agent-scope stores (distinct addresses) + 1 release
// counter-add per block; the 256th block acquire-invalidates, reduces the
// 512 partials in one wave, and plain-stores d_out. No spins, no d_out RMW.
// grid = 256, block = 512; wave wv owns K-slice [wv*128, wv*128+128).
// ---------------------------------------------------------------------------
__global__ __launch_bounds__(512) void gemm_kernel(
    const float* __restrict__ x, const unsigned short* __restrict__ phi,
    const float* __restrict__ pnorm4, float* __restrict__ part,
    unsigned* __restrict__ ctr, float* __restrict__ out) {
  __shared__ float Sp[8][16][68];   // per-wave partial tiles (padded)
  __shared__ float So[16][68];      // reduced logits
  __shared__ float pnL[64];

  const int tid  = threadIdx.x;
  const int wv   = tid >> 6;
  const int lane = tid & 63;
  const int lrow = lane & 15;
  const int kgrp = lane >> 4;
  const int qb   = blockIdx.x * QT;

  // ---- A loads first (HBM-bound: start early), then B (LLC-hot) ----
  const int qrow = (qb >> 6) * ROWS_PER_WAY + N_SUP + (qb & 63) + lrow;
  const float* arow = x + (size_t)qrow * DIM + kgrp * 8;
  f32x4 a0[4], a1[4];
  #pragma unroll
  for (int s = 0; s < 4; ++s) {
    a0[s] = *(const f32x4*)(arow + (wv * 4 + s) * 32);
    a1[s] = *(const f32x4*)(arow + (wv * 4 + s) * 32 + 4);
  }
  const short8* bhp = (const short8*)phi + lane;
  short8 bhv[4][4];
  #pragma unroll
  for (int s = 0; s < 4; ++s)
    #pragma unroll
    for (int t = 0; t < 4; ++t)
      bhv[s][t] = bhp[((wv * 4 + s) * 4 + t) * 64];

  if (tid < 64)
    pnL[tid] = pnorm4[4 * tid] + pnorm4[4 * tid + 1] +
               pnorm4[4 * tid + 2] + pnorm4[4 * tid + 3];

  // ---- convert A to bf16 (RNE) ----
  short8 ah[4];
  #pragma unroll
  for (int s = 0; s < 4; ++s)
    #pragma unroll
    for (int j = 0; j < 4; ++j) {
      ah[s][j]     = (short)bf16_rne(a0[s][j]);
      ah[s][4 + j] = (short)bf16_rne(a1[s][j]);
    }

  // ---- 16 MFMAs ----
  f32x4 acc[4];
  #pragma unroll
  for (int t = 0; t < 4; ++t) acc[t] = (f32x4){0.f, 0.f, 0.f, 0.f};
  #pragma unroll
  for (int s = 0; s < 4; ++s)
    #pragma unroll
    for (int t = 0; t < 4; ++t)
      acc[t] = __builtin_amdgcn_mfma_f32_16x16x32_bf16(ah[s], bhv[s][t], acc[t], 0, 0, 0);

  // per-wave partials: C/D layout col(way)=lane&15, row(q)=kgrp*4+r (validated)
  #pragma unroll
  for (int t = 0; t < 4; ++t)
    #pragma unroll
    for (int r = 0; r < 4; ++r)
      Sp[wv][kgrp * 4 + r][t * 16 + lrow] = acc[t][r];
  __syncthreads();

  // reduce 8 K-slices, apply 2*dot - pnorm
  for (int i = tid; i < QT * N_WAY; i += 512) {
    int q = i >> 6, w = i & 63;
    float s = 0.f;
    #pragma unroll
    for (int v = 0; v < 8; ++v) s += Sp[v][q][w];
    So[q][w] = 2.f * s - pnL[w];
  }
  __syncthreads();

  // fused log-softmax + argmax: wave 0, 64 lanes = 16 q x 4 way-quarters
  if (tid < 64) {
    const int q = lane & 15;
    const int wq = lane >> 4;
    const int label = qb >> 6;
    float m = -INFINITY; int arg = 0;
    #pragma unroll
    for (int i = 0; i < 16; ++i) {
      int w = wq * 16 + i;
      float v = So[q][w];
      if (v > m) { m = v; arg = w; }
    }
    #pragma unroll
    for (int off = 16; off < 64; off <<= 1) {
      float om = __shfl_xor(m, off);
      int oa = __shfl_xor(arg, off);
      if (om > m || (om == m && oa < arg)) { m = om; arg = oa; }
    }
    float sum = 0.f;
    #pragma unroll
    for (int i = 0; i < 16; ++i) sum += expf(So[q][wq * 16 + i] - m);
    sum += __shfl_xor(sum, 16);
    sum += __shfl_xor(sum, 32);

    float lossq = 0.f, corr = 0.f;
    if (lane < 16) {
      lossq = m + logf(sum) - So[q][label];
      corr = (arg == label) ? 1.f : 0.f;
    }
    #pragma unroll
    for (int off = 8; off > 0; off >>= 1) {
      lossq += __shfl_down(lossq, off);
      corr  += __shfl_down(corr, off);
    }

    // ---- tail: publish partials, last block reduces ----
    unsigned old = 0u;
    if (lane == 0) {
      __hip_atomic_store(&part[2 * blockIdx.x],     lossq, __ATOMIC_RELAXED,
                         __HIP_MEMORY_SCOPE_AGENT);
      __hip_atomic_store(&part[2 * blockIdx.x + 1], corr,  __ATOMIC_RELAXED,
                         __HIP_MEMORY_SCOPE_AGENT);
      old = __hip_atomic_fetch_add(ctr, 1u, __ATOMIC_RELEASE,
                                   __HIP_MEMORY_SCOPE_AGENT);
    }
    old = __shfl(old, 0);
    if (old == GEMM_BLOCKS - 1) {       // last block: everyone else published
      if (lane == 0)
        (void)__hip_atomic_load(ctr, __ATOMIC_ACQUIRE, __HIP_MEMORY_SCOPE_AGENT);
      __builtin_amdgcn_wave_barrier();  // acquire (cache inv) before the reads
      const float4* p4 = (const float4*)part;   // 128 float4
      float4 v0 = p4[lane], v1 = p4[64 + lane];
      float l = v0.x + v0.z + v1.x + v1.z;
      float c = v0.y + v0.w + v1.y + v1.w;
      #pragma unroll
      for (int off = 32; off > 0; off >>= 1) {
        l += __shfl_down(l, off);
        c += __shfl_down(c, off);
      }
      if (lane == 0) {
        out[0] = l * (1.0f / (float)N_QUERIES);
        out[1] = c * (100.0f / (float)N_QUERIES);
      }
    }
  }
}

extern "C" void kernel_launch(void* const* d_in, const int* in_sizes, int n_in,
                              void* d_out, int out_size, void* d_ws, size_t ws_size,
                              hipStream_t stream) {
  (void)in_sizes; (void)n_in; (void)out_size; (void)ws_size;
  const float* x = (const float*)d_in[0];
  float* out = (float*)d_out;

  unsigned short* phi = (unsigned short*)d_ws;        // 64*1024 u16 packed
  float* pnorm4 = (float*)(phi + N_WAY * DIM);        // 256 f32
  float* part   = pnorm4 + 256;                       // 512 f32
  unsigned* ctr = (unsigned*)(part + 2 * GEMM_BLOCKS);// 1 u32

  hipLaunchKernelGGL(proto_kernel, dim3(256), dim3(256), 0, stream,
                     x, phi, pnorm4, ctr);
  hipLaunchKernelGGL(gemm_kernel, dim3(GEMM_BLOCKS), dim3(512), 0, stream,
                     x, phi, pnorm4, part, ctr, out);
}

// Round 9
// 18.870 us; speedup vs baseline: 1.1622x; 1.0779x over previous
//
#include <hip/hip_runtime.h>
#include <math.h>

#define N_WAY 64
#define N_SUP 16
#define DIM   1024
#define N_QUERIES 4096
#define ROWS_PER_WAY 80
#define QT 16
#define GEMM_BLOCKS 256   // N_QUERIES / QT

typedef __attribute__((ext_vector_type(8))) short short8;
typedef __attribute__((ext_vector_type(4))) float f32x4;

// bf16 round-to-nearest-even
__device__ __forceinline__ unsigned short bf16_rne(float f) {
  unsigned u = __float_as_uint(f);
  return (unsigned short)((u + 0x7fffu + ((u >> 16) & 1u)) >> 16);
}

// Packed B-fragment layout (validated round 3): short8 index (kb*4+tile)*64+lane,
// lane = kgrp*16 + n15 holds way tile*16+n15, k = kb*32 + kgrp*8 + j.

// ---------------------------------------------------------------------------
// Kernel A: prototypes -> packed bf16 fragments + per-quarter pnorm partials.
// grid = 256 (4 blocks per way), block = 256. No atomics. Zeroes the
// completion counter (plain store; node-boundary release makes it visible).
// ---------------------------------------------------------------------------
__global__ __launch_bounds__(256) void proto_kernel(
    const float* __restrict__ x, unsigned short* __restrict__ phi,
    float* __restrict__ pnorm4, unsigned* __restrict__ ctr) {
  const int way = blockIdx.x >> 2;
  const int cg  = blockIdx.x & 3;       // column quarter
  const int t   = threadIdx.x;
  const int lc  = t & 63;               // local f32x4 col
  const int sg  = t >> 6;               // support group (4 rows)
  const float4* x4 = (const float4*)x;
  const int base = way * ROWS_PER_WAY * (DIM / 4);
  const int col = cg * 64 + lc;         // f32x4 col 0..255

  if (blockIdx.x == 0 && t == 0) *ctr = 0u;   // replay-safe reset

  float4 a = make_float4(0.f, 0.f, 0.f, 0.f);
  #pragma unroll
  for (int r = 0; r < 4; ++r) {
    float4 v = x4[base + (sg * 4 + r) * (DIM / 4) + col];
    a.x += v.x; a.y += v.y; a.z += v.z; a.w += v.w;
  }
  __shared__ float4 pars[4][64];
  pars[sg][lc] = a;
  __syncthreads();

  if (t < 64) {
    float4 a0 = pars[0][t], a1 = pars[1][t], a2 = pars[2][t], a3 = pars[3][t];
    const float inv = 1.0f / 16.0f;
    float vals[4] = {(a0.x + a1.x + a2.x + a3.x) * inv,
                     (a0.y + a1.y + a2.y + a3.y) * inv,
                     (a0.z + a1.z + a2.z + a3.z) * inv,
                     (a0.w + a1.w + a2.w + a3.w) * inv};
    const int c   = cg * 64 + t;        // f32x4 col 0..255
    const int kb2 = c >> 3, kg2 = (c >> 1) & 3, j0 = (c & 1) * 4;
    const int tile = way >> 4;
    const int ln = kg2 * 16 + (way & 15);
    const int uidx = ((kb2 * 4 + tile) * 64 + ln) * 8 + j0;
    *(ushort4*)(phi + uidx) = make_ushort4(bf16_rne(vals[0]), bf16_rne(vals[1]),
                                           bf16_rne(vals[2]), bf16_rne(vals[3]));

    float pq = vals[0] * vals[0] + vals[1] * vals[1] +
               vals[2] * vals[2] + vals[3] * vals[3];
    #pragma unroll
    for (int off = 32; off > 0; off >>= 1) pq += __shfl_down(pq, off);
    if (t == 0) pnorm4[way * 4 + cg] = pq;   // plain store, no atomic
  }
}

// ---------------------------------------------------------------------------
// Kernel B: bf16 MFMA gemm + fused per-tile softmax + RELAXED last-block
// finalize. Per block: 2 relaxed agent stores (distinct addrs, -> LLC),
// s_waitcnt to order them, 1 RELAXED fetch-add on ctr (no wbl2!). The block
// seeing old==255 reads partials back via relaxed agent loads (LLC is the
// coherence point) and plain-stores d_out. No fences, no spins, no d_out RMW.
// ---------------------------------------------------------------------------
__global__ __launch_bounds__(512) void gemm_kernel(
    const float* __restrict__ x, const unsigned short* __restrict__ phi,
    const float* __restrict__ pnorm4, float* __restrict__ part,
    unsigned* __restrict__ ctr, float* __restrict__ out) {
  __shared__ float Sp[8][16][68];   // per-wave partial tiles (padded)
  __shared__ float So[16][68];      // reduced logits
  __shared__ float pnL[64];

  const int tid  = threadIdx.x;
  const int wv   = tid >> 6;
  const int lane = tid & 63;
  const int lrow = lane & 15;
  const int kgrp = lane >> 4;
  const int qb   = blockIdx.x * QT;

  // ---- A loads first (HBM-bound: start early), then B (LLC-hot) ----
  const int qrow = (qb >> 6) * ROWS_PER_WAY + N_SUP + (qb & 63) + lrow;
  const float* arow = x + (size_t)qrow * DIM + kgrp * 8;
  f32x4 a0[4], a1[4];
  #pragma unroll
  for (int s = 0; s < 4; ++s) {
    a0[s] = *(const f32x4*)(arow + (wv * 4 + s) * 32);
    a1[s] = *(const f32x4*)(arow + (wv * 4 + s) * 32 + 4);
  }
  const short8* bhp = (const short8*)phi + lane;
  short8 bhv[4][4];
  #pragma unroll
  for (int s = 0; s < 4; ++s)
    #pragma unroll
    for (int t = 0; t < 4; ++t)
      bhv[s][t] = bhp[((wv * 4 + s) * 4 + t) * 64];

  if (tid < 64)
    pnL[tid] = pnorm4[4 * tid] + pnorm4[4 * tid + 1] +
               pnorm4[4 * tid + 2] + pnorm4[4 * tid + 3];

  // ---- convert A to bf16 (RNE) ----
  short8 ah[4];
  #pragma unroll
  for (int s = 0; s < 4; ++s)
    #pragma unroll
    for (int j = 0; j < 4; ++j) {
      ah[s][j]     = (short)bf16_rne(a0[s][j]);
      ah[s][4 + j] = (short)bf16_rne(a1[s][j]);
    }

  // ---- 16 MFMAs ----
  f32x4 acc[4];
  #pragma unroll
  for (int t = 0; t < 4; ++t) acc[t] = (f32x4){0.f, 0.f, 0.f, 0.f};
  #pragma unroll
  for (int s = 0; s < 4; ++s)
    #pragma unroll
    for (int t = 0; t < 4; ++t)
      acc[t] = __builtin_amdgcn_mfma_f32_16x16x32_bf16(ah[s], bhv[s][t], acc[t], 0, 0, 0);

  // per-wave partials: C/D layout col(way)=lane&15, row(q)=kgrp*4+r (validated)
  #pragma unroll
  for (int t = 0; t < 4; ++t)
    #pragma unroll
    for (int r = 0; r < 4; ++r)
      Sp[wv][kgrp * 4 + r][t * 16 + lrow] = acc[t][r];
  __syncthreads();

  // reduce 8 K-slices, apply 2*dot - pnorm
  for (int i = tid; i < QT * N_WAY; i += 512) {
    int q = i >> 6, w = i & 63;
    float s = 0.f;
    #pragma unroll
    for (int v = 0; v < 8; ++v) s += Sp[v][q][w];
    So[q][w] = 2.f * s - pnL[w];
  }
  __syncthreads();

  // fused log-softmax + argmax: wave 0, 64 lanes = 16 q x 4 way-quarters
  if (tid < 64) {
    const int q = lane & 15;
    const int wq = lane >> 4;
    const int label = qb >> 6;
    float m = -INFINITY; int arg = 0;
    #pragma unroll
    for (int i = 0; i < 16; ++i) {
      int w = wq * 16 + i;
      float v = So[q][w];
      if (v > m) { m = v; arg = w; }
    }
    #pragma unroll
    for (int off = 16; off < 64; off <<= 1) {
      float om = __shfl_xor(m, off);
      int oa = __shfl_xor(arg, off);
      if (om > m || (om == m && oa < arg)) { m = om; arg = oa; }
    }
    float sum = 0.f;
    #pragma unroll
    for (int i = 0; i < 16; ++i) sum += expf(So[q][wq * 16 + i] - m);
    sum += __shfl_xor(sum, 16);
    sum += __shfl_xor(sum, 32);

    float lossq = 0.f, corr = 0.f;
    if (lane < 16) {
      lossq = m + logf(sum) - So[q][label];
      corr = (arg == label) ? 1.f : 0.f;
    }
    #pragma unroll
    for (int off = 8; off > 0; off >>= 1) {
      lossq += __shfl_down(lossq, off);
      corr  += __shfl_down(corr, off);
    }

    // ---- tail: relaxed publish + relaxed counter; last block reduces ----
    unsigned old = 0u;
    if (lane == 0) {
      __hip_atomic_store(&part[2 * blockIdx.x],     lossq, __ATOMIC_RELAXED,
                         __HIP_MEMORY_SCOPE_AGENT);
      __hip_atomic_store(&part[2 * blockIdx.x + 1], corr,  __ATOMIC_RELAXED,
                         __HIP_MEMORY_SCOPE_AGENT);
      asm volatile("s_waitcnt vmcnt(0)" ::: "memory");  // stores reach LLC first
      old = __hip_atomic_fetch_add(ctr, 1u, __ATOMIC_RELAXED,
                                   __HIP_MEMORY_SCOPE_AGENT);
    }
    old = __shfl(old, 0);
    if (old == GEMM_BLOCKS - 1) {   // last: all publishes are in LLC
      float l = 0.f, c = 0.f;
      #pragma unroll
      for (int r = 0; r < 4; ++r) {
        int i = lane + 64 * r;      // partial-pair index 0..255
        l += __hip_atomic_load(&part[2 * i],     __ATOMIC_RELAXED,
                               __HIP_MEMORY_SCOPE_AGENT);
        c += __hip_atomic_load(&part[2 * i + 1], __ATOMIC_RELAXED,
                               __HIP_MEMORY_SCOPE_AGENT);
      }
      #pragma unroll
      for (int off = 32; off > 0; off >>= 1) {
        l += __shfl_down(l, off);
        c += __shfl_down(c, off);
      }
      if (lane == 0) {
        out[0] = l * (1.0f / (float)N_QUERIES);
        out[1] = c * (100.0f / (float)N_QUERIES);
      }
    }
  }
}

extern "C" void kernel_launch(void* const* d_in, const int* in_sizes, int n_in,
                              void* d_out, int out_size, void* d_ws, size_t ws_size,
                              hipStream_t stream) {
  (void)in_sizes; (void)n_in; (void)out_size; (void)ws_size;
  const float* x = (const float*)d_in[0];
  float* out = (float*)d_out;

  unsigned short* phi = (unsigned short*)d_ws;        // 64*1024 u16 packed
  float* pnorm4 = (float*)(phi + N_WAY * DIM);        // 256 f32
  float* part   = pnorm4 + 256;                       // 512 f32
  unsigned* ctr = (unsigned*)(part + 2 * GEMM_BLOCKS);// 1 u32

  hipLaunchKernelGGL(proto_kernel, dim3(256), dim3(256), 0, stream,
                     x, phi, pnorm4, ctr);
  hipLaunchKernelGGL(gemm_kernel, dim3(GEMM_BLOCKS), dim3(512), 0, stream,
                     x, phi, pnorm4, part, ctr, out);
}

// Round 10
// 17.171 us; speedup vs baseline: 1.2772x; 1.0989x over previous
//
#include <hip/hip_runtime.h>
#include <math.h>

#define N_WAY 64
#define N_SUP 16
#define DIM   1024
#define N_QUERIES 4096
#define ROWS_PER_WAY 80
#define QT 16
#define GEMM_BLOCKS 256   // N_QUERIES / QT
#define NLEAF 32          // leaf counters, 8 blocks each
#define CTR_STRIDE 32     // u32 stride = 128B = one cacheline per counter

typedef __attribute__((ext_vector_type(8))) short short8;
typedef __attribute__((ext_vector_type(4))) float f32x4;

// bf16 round-to-nearest-even
__device__ __forceinline__ unsigned short bf16_rne(float f) {
  unsigned u = __float_as_uint(f);
  return (unsigned short)((u + 0x7fffu + ((u >> 16) & 1u)) >> 16);
}

// Packed B-fragment layout (validated round 3): short8 index (kb*4+tile)*64+lane,
// lane = kgrp*16 + n15 holds way tile*16+n15, k = kb*32 + kgrp*8 + j.

// ---------------------------------------------------------------------------
// Kernel A: prototypes -> packed bf16 fragments + per-quarter pnorm partials.
// grid = 256 (4 blocks per way), block = 256. No atomics. Zeroes the 33
// tree counters (plain stores; node-boundary release publishes them).
// ---------------------------------------------------------------------------
__global__ __launch_bounds__(256) void proto_kernel(
    const float* __restrict__ x, unsigned short* __restrict__ phi,
    float* __restrict__ pnorm4, unsigned* __restrict__ ctrs) {
  const int way = blockIdx.x >> 2;
  const int cg  = blockIdx.x & 3;       // column quarter
  const int t   = threadIdx.x;
  const int lc  = t & 63;               // local f32x4 col
  const int sg  = t >> 6;               // support group (4 rows)
  const float4* x4 = (const float4*)x;
  const int base = way * ROWS_PER_WAY * (DIM / 4);
  const int col = cg * 64 + lc;         // f32x4 col 0..255

  if (blockIdx.x == 0 && t <= NLEAF) ctrs[t * CTR_STRIDE] = 0u;  // replay-safe

  float4 a = make_float4(0.f, 0.f, 0.f, 0.f);
  #pragma unroll
  for (int r = 0; r < 4; ++r) {
    float4 v = x4[base + (sg * 4 + r) * (DIM / 4) + col];
    a.x += v.x; a.y += v.y; a.z += v.z; a.w += v.w;
  }
  __shared__ float4 pars[4][64];
  pars[sg][lc] = a;
  __syncthreads();

  if (t < 64) {
    float4 a0 = pars[0][t], a1 = pars[1][t], a2 = pars[2][t], a3 = pars[3][t];
    const float inv = 1.0f / 16.0f;
    float vals[4] = {(a0.x + a1.x + a2.x + a3.x) * inv,
                     (a0.y + a1.y + a2.y + a3.y) * inv,
                     (a0.z + a1.z + a2.z + a3.z) * inv,
                     (a0.w + a1.w + a2.w + a3.w) * inv};
    const int c   = cg * 64 + t;        // f32x4 col 0..255
    const int kb2 = c >> 3, kg2 = (c >> 1) & 3, j0 = (c & 1) * 4;
    const int tile = way >> 4;
    const int ln = kg2 * 16 + (way & 15);
    const int uidx = ((kb2 * 4 + tile) * 64 + ln) * 8 + j0;
    *(ushort4*)(phi + uidx) = make_ushort4(bf16_rne(vals[0]), bf16_rne(vals[1]),
                                           bf16_rne(vals[2]), bf16_rne(vals[3]));

    float pq = vals[0] * vals[0] + vals[1] * vals[1] +
               vals[2] * vals[2] + vals[3] * vals[3];
    #pragma unroll
    for (int off = 32; off > 0; off >>= 1) pq += __shfl_down(pq, off);
    if (t == 0) pnorm4[way * 4 + cg] = pq;   // plain store, no atomic
  }
}

// ---------------------------------------------------------------------------
// Kernel B: bf16 MFMA gemm + fused softmax + tree-tail last-block finalize.
// Publish: 2 relaxed agent stores (distinct addrs) + vmcnt(0). Arrival: leaf
// fetch-add (blk&31, own cacheline, <=8-way) -> leaf-last does root fetch-add
// (32-way). Root-last (all publishes in LLC by transitivity) reduces via
// relaxed loads, plain-stores d_out. No fences, no spins, no same-line storm.
// ---------------------------------------------------------------------------
__global__ __launch_bounds__(512) void gemm_kernel(
    const float* __restrict__ x, const unsigned short* __restrict__ phi,
    const float* __restrict__ pnorm4, float* __restrict__ part,
    unsigned* __restrict__ ctrs, float* __restrict__ out) {
  __shared__ float Sp[8][16][68];   // per-wave partial tiles (padded)
  __shared__ float So[16][68];      // reduced logits
  __shared__ float pnL[64];

  const int tid  = threadIdx.x;
  const int wv   = tid >> 6;
  const int lane = tid & 63;
  const int lrow = lane & 15;
  const int kgrp = lane >> 4;
  const int qb   = blockIdx.x * QT;

  // ---- A loads first (HBM-bound: start early), then B (LLC/L2-hot) ----
  const int qrow = (qb >> 6) * ROWS_PER_WAY + N_SUP + (qb & 63) + lrow;
  const float* arow = x + (size_t)qrow * DIM + kgrp * 8;
  f32x4 a0[4], a1[4];
  #pragma unroll
  for (int s = 0; s < 4; ++s) {
    a0[s] = *(const f32x4*)(arow + (wv * 4 + s) * 32);
    a1[s] = *(const f32x4*)(arow + (wv * 4 + s) * 32 + 4);
  }
  const short8* bhp = (const short8*)phi + lane;
  short8 bhv[4][4];
  #pragma unroll
  for (int s = 0; s < 4; ++s)
    #pragma unroll
    for (int t = 0; t < 4; ++t)
      bhv[s][t] = bhp[((wv * 4 + s) * 4 + t) * 64];

  if (tid < 64)
    pnL[tid] = pnorm4[4 * tid] + pnorm4[4 * tid + 1] +
               pnorm4[4 * tid + 2] + pnorm4[4 * tid + 3];

  // ---- convert A to bf16 (RNE) ----
  short8 ah[4];
  #pragma unroll
  for (int s = 0; s < 4; ++s)
    #pragma unroll
    for (int j = 0; j < 4; ++j) {
      ah[s][j]     = (short)bf16_rne(a0[s][j]);
      ah[s][4 + j] = (short)bf16_rne(a1[s][j]);
    }

  // ---- 16 MFMAs ----
  f32x4 acc[4];
  #pragma unroll
  for (int t = 0; t < 4; ++t) acc[t] = (f32x4){0.f, 0.f, 0.f, 0.f};
  #pragma unroll
  for (int s = 0; s < 4; ++s)
    #pragma unroll
    for (int t = 0; t < 4; ++t)
      acc[t] = __builtin_amdgcn_mfma_f32_16x16x32_bf16(ah[s], bhv[s][t], acc[t], 0, 0, 0);

  // per-wave partials: C/D layout col(way)=lane&15, row(q)=kgrp*4+r (validated)
  #pragma unroll
  for (int t = 0; t < 4; ++t)
    #pragma unroll
    for (int r = 0; r < 4; ++r)
      Sp[wv][kgrp * 4 + r][t * 16 + lrow] = acc[t][r];
  __syncthreads();

  // reduce 8 K-slices, apply 2*dot - pnorm
  for (int i = tid; i < QT * N_WAY; i += 512) {
    int q = i >> 6, w = i & 63;
    float s = 0.f;
    #pragma unroll
    for (int v = 0; v < 8; ++v) s += Sp[v][q][w];
    So[q][w] = 2.f * s - pnL[w];
  }
  __syncthreads();

  // fused log-softmax + argmax: wave 0, 64 lanes = 16 q x 4 way-quarters
  if (tid < 64) {
    const int q = lane & 15;
    const int wq = lane >> 4;
    const int label = qb >> 6;
    float m = -INFINITY; int arg = 0;
    #pragma unroll
    for (int i = 0; i < 16; ++i) {
      int w = wq * 16 + i;
      float v = So[q][w];
      if (v > m) { m = v; arg = w; }
    }
    #pragma unroll
    for (int off = 16; off < 64; off <<= 1) {
      float om = __shfl_xor(m, off);
      int oa = __shfl_xor(arg, off);
      if (om > m || (om == m && oa < arg)) { m = om; arg = oa; }
    }
    float sum = 0.f;
    #pragma unroll
    for (int i = 0; i < 16; ++i) sum += expf(So[q][wq * 16 + i] - m);
    sum += __shfl_xor(sum, 16);
    sum += __shfl_xor(sum, 32);

    float lossq = 0.f, corr = 0.f;
    if (lane < 16) {
      lossq = m + logf(sum) - So[q][label];
      corr = (arg == label) ? 1.f : 0.f;
    }
    #pragma unroll
    for (int off = 8; off > 0; off >>= 1) {
      lossq += __shfl_down(lossq, off);
      corr  += __shfl_down(corr, off);
    }

    // ---- tree tail: publish, leaf arrival, root arrival, last reduces ----
    int last = 0;
    if (lane == 0) {
      __hip_atomic_store(&part[2 * blockIdx.x],     lossq, __ATOMIC_RELAXED,
                         __HIP_MEMORY_SCOPE_AGENT);
      __hip_atomic_store(&part[2 * blockIdx.x + 1], corr,  __ATOMIC_RELAXED,
                         __HIP_MEMORY_SCOPE_AGENT);
      asm volatile("s_waitcnt vmcnt(0)" ::: "memory");  // publishes reach LLC
      unsigned leaf = (unsigned)(blockIdx.x & (NLEAF - 1));
      unsigned ol = __hip_atomic_fetch_add(&ctrs[leaf * CTR_STRIDE], 1u,
                                           __ATOMIC_RELAXED,
                                           __HIP_MEMORY_SCOPE_AGENT);
      if (ol == (GEMM_BLOCKS / NLEAF) - 1) {   // leaf-last (8th of this leaf)
        unsigned orr = __hip_atomic_fetch_add(&ctrs[NLEAF * CTR_STRIDE], 1u,
                                              __ATOMIC_RELAXED,
                                              __HIP_MEMORY_SCOPE_AGENT);
        last = (orr == NLEAF - 1);
      }
    }
    last = __shfl(last, 0);
    if (last) {   // all 256 publishes are in LLC (counter transitivity)
      float l = 0.f, c = 0.f;
      #pragma unroll
      for (int r = 0; r < 4; ++r) {
        int i = lane + 64 * r;      // partial-pair index 0..255
        l += __hip_atomic_load(&part[2 * i],     __ATOMIC_RELAXED,
                               __HIP_MEMORY_SCOPE_AGENT);
        c += __hip_atomic_load(&part[2 * i + 1], __ATOMIC_RELAXED,
                               __HIP_MEMORY_SCOPE_AGENT);
      }
      #pragma unroll
      for (int off = 32; off > 0; off >>= 1) {
        l += __shfl_down(l, off);
        c += __shfl_down(c, off);
      }
      if (lane == 0) {
        out[0] = l * (1.0f / (float)N_QUERIES);
        out[1] = c * (100.0f / (float)N_QUERIES);
      }
    }
  }
}

extern "C" void kernel_launch(void* const* d_in, const int* in_sizes, int n_in,
                              void* d_out, int out_size, void* d_ws, size_t ws_size,
                              hipStream_t stream) {
  (void)in_sizes; (void)n_in; (void)out_size; (void)ws_size;
  const float* x = (const float*)d_in[0];
  float* out = (float*)d_out;

  unsigned short* phi = (unsigned short*)d_ws;        // 64*1024 u16 packed
  float* pnorm4 = (float*)(phi + N_WAY * DIM);        // 256 f32
  float* part   = pnorm4 + 256;                       // 512 f32
  unsigned* ctrs = (unsigned*)(part + 2 * GEMM_BLOCKS); // 33 x 128B-strided u32

  hipLaunchKernelGGL(proto_kernel, dim3(256), dim3(256), 0, stream,
                     x, phi, pnorm4, ctrs);
  hipLaunchKernelGGL(gemm_kernel, dim3(GEMM_BLOCKS), dim3(512), 0, stream,
                     x, phi, pnorm4, part, ctrs, out);
}

// Round 11
// 16.728 us; speedup vs baseline: 1.3111x; 1.0265x over previous
//
#include <hip/hip_runtime.h>
#include <math.h>

#define N_WAY 64
#define N_SUP 16
#define DIM   1024
#define N_QUERIES 4096
#define ROWS_PER_WAY 80
#define QT 16
#define GEMM_BLOCKS 256   // worker blocks (N_QUERIES / QT); +1 finalizer
#define NLEAF 32          // leaf counters, 8 workers each
#define CTR_STRIDE 32     // u32 stride = 128B = one cacheline per counter

typedef __attribute__((ext_vector_type(8))) short short8;
typedef __attribute__((ext_vector_type(4))) float f32x4;

// bf16 round-to-nearest-even
__device__ __forceinline__ unsigned short bf16_rne(float f) {
  unsigned u = __float_as_uint(f);
  return (unsigned short)((u + 0x7fffu + ((u >> 16) & 1u)) >> 16);
}

// Packed B-fragment layout (validated round 3): short8 index (kb*4+tile)*64+lane,
// lane = kgrp*16 + n15 holds way tile*16+n15, k = kb*32 + kgrp*8 + j.

// ---------------------------------------------------------------------------
// Kernel A: prototypes -> packed bf16 fragments + per-quarter pnorm partials.
// grid = 256 (4 blocks per way), block = 256. No atomics. Zeroes the 33
// tree counters (plain stores; node-boundary release publishes them).
// ---------------------------------------------------------------------------
__global__ __launch_bounds__(256) void proto_kernel(
    const float* __restrict__ x, unsigned short* __restrict__ phi,
    float* __restrict__ pnorm4, unsigned* __restrict__ ctrs) {
  const int way = blockIdx.x >> 2;
  const int cg  = blockIdx.x & 3;       // column quarter
  const int t   = threadIdx.x;
  const int lc  = t & 63;               // local f32x4 col
  const int sg  = t >> 6;               // support group (4 rows)
  const float4* x4 = (const float4*)x;
  const int base = way * ROWS_PER_WAY * (DIM / 4);
  const int col = cg * 64 + lc;         // f32x4 col 0..255

  if (blockIdx.x == 0 && t <= NLEAF) ctrs[t * CTR_STRIDE] = 0u;  // replay-safe

  float4 a = make_float4(0.f, 0.f, 0.f, 0.f);
  #pragma unroll
  for (int r = 0; r < 4; ++r) {
    float4 v = x4[base + (sg * 4 + r) * (DIM / 4) + col];
    a.x += v.x; a.y += v.y; a.z += v.z; a.w += v.w;
  }
  __shared__ float4 pars[4][64];
  pars[sg][lc] = a;
  __syncthreads();

  if (t < 64) {
    float4 a0 = pars[0][t], a1 = pars[1][t], a2 = pars[2][t], a3 = pars[3][t];
    const float inv = 1.0f / 16.0f;
    float vals[4] = {(a0.x + a1.x + a2.x + a3.x) * inv,
                     (a0.y + a1.y + a2.y + a3.y) * inv,
                     (a0.z + a1.z + a2.z + a3.z) * inv,
                     (a0.w + a1.w + a2.w + a3.w) * inv};
    const int c   = cg * 64 + t;        // f32x4 col 0..255
    const int kb2 = c >> 3, kg2 = (c >> 1) & 3, j0 = (c & 1) * 4;
    const int tile = way >> 4;
    const int ln = kg2 * 16 + (way & 15);
    const int uidx = ((kb2 * 4 + tile) * 64 + ln) * 8 + j0;
    *(ushort4*)(phi + uidx) = make_ushort4(bf16_rne(vals[0]), bf16_rne(vals[1]),
                                           bf16_rne(vals[2]), bf16_rne(vals[3]));

    float pq = vals[0] * vals[0] + vals[1] * vals[1] +
               vals[2] * vals[2] + vals[3] * vals[3];
    #pragma unroll
    for (int off = 32; off > 0; off >>= 1) pq += __shfl_down(pq, off);
    if (t == 0) pnorm4[way * 4 + cg] = pq;   // plain store, no atomic
  }
}

// ---------------------------------------------------------------------------
// Kernel B: grid = 257. Block 0 = finalizer: relax-polls the tree root while
// workers compute; on root==NLEAF, relax-loads the 512 partials (LLC is the
// coherence point — mechanism validated R9/R10) and plain-stores d_out.
// Blocks 1..256 = workers: bf16 MFMA gemm + fused softmax, publish partials
// (relaxed stores + vmcnt(0)), leaf fetch-add; leaf-last bumps root. No
// fences, no d_out RMW, no post-straggler RMW chain on the critical path.
// ---------------------------------------------------------------------------
__global__ __launch_bounds__(512) void gemm_kernel(
    const float* __restrict__ x, const unsigned short* __restrict__ phi,
    const float* __restrict__ pnorm4, float* __restrict__ part,
    unsigned* __restrict__ ctrs, float* __restrict__ out) {
  const int tid  = threadIdx.x;
  const int lane = tid & 63;

  if (blockIdx.x == 0) {
    // ---------------- finalizer block ----------------
    if (tid < 64) {
      if (lane == 0) {
        while (__hip_atomic_load(&ctrs[NLEAF * CTR_STRIDE], __ATOMIC_RELAXED,
                                 __HIP_MEMORY_SCOPE_AGENT) < NLEAF)
          __builtin_amdgcn_s_sleep(2);
      }
      // reconverged: all 256 publishes are in LLC
      float l = 0.f, c = 0.f;
      #pragma unroll
      for (int r = 0; r < 4; ++r) {
        int i = lane + 64 * r;      // partial-pair index 0..255
        l += __hip_atomic_load(&part[2 * i],     __ATOMIC_RELAXED,
                               __HIP_MEMORY_SCOPE_AGENT);
        c += __hip_atomic_load(&part[2 * i + 1], __ATOMIC_RELAXED,
                               __HIP_MEMORY_SCOPE_AGENT);
      }
      #pragma unroll
      for (int off = 32; off > 0; off >>= 1) {
        l += __shfl_down(l, off);
        c += __shfl_down(c, off);
      }
      if (lane == 0) {
        out[0] = l * (1.0f / (float)N_QUERIES);
        out[1] = c * (100.0f / (float)N_QUERIES);
      }
    }
    return;
  }

  // ---------------- worker blocks ----------------
  __shared__ float Sp[8][16][68];   // per-wave partial tiles (padded)
  __shared__ float So[16][68];      // reduced logits
  __shared__ float pnL[64];

  const int blk  = blockIdx.x - 1;  // 0..255
  const int wv   = tid >> 6;
  const int lrow = lane & 15;
  const int kgrp = lane >> 4;
  const int qb   = blk * QT;

  // ---- A loads first (HBM-bound: start early), then B (LLC/L2-hot) ----
  const int qrow = (qb >> 6) * ROWS_PER_WAY + N_SUP + (qb & 63) + lrow;
  const float* arow = x + (size_t)qrow * DIM + kgrp * 8;
  f32x4 a0[4], a1[4];
  #pragma unroll
  for (int s = 0; s < 4; ++s) {
    a0[s] = *(const f32x4*)(arow + (wv * 4 + s) * 32);
    a1[s] = *(const f32x4*)(arow + (wv * 4 + s) * 32 + 4);
  }
  const short8* bhp = (const short8*)phi + lane;
  short8 bhv[4][4];
  #pragma unroll
  for (int s = 0; s < 4; ++s)
    #pragma unroll
    for (int t = 0; t < 4; ++t)
      bhv[s][t] = bhp[((wv * 4 + s) * 4 + t) * 64];

  if (tid < 64)
    pnL[tid] = pnorm4[4 * tid] + pnorm4[4 * tid + 1] +
               pnorm4[4 * tid + 2] + pnorm4[4 * tid + 3];

  // ---- convert A to bf16 (RNE) ----
  short8 ah[4];
  #pragma unroll
  for (int s = 0; s < 4; ++s)
    #pragma unroll
    for (int j = 0; j < 4; ++j) {
      ah[s][j]     = (short)bf16_rne(a0[s][j]);
      ah[s][4 + j] = (short)bf16_rne(a1[s][j]);
    }

  // ---- 16 MFMAs ----
  f32x4 acc[4];
  #pragma unroll
  for (int t = 0; t < 4; ++t) acc[t] = (f32x4){0.f, 0.f, 0.f, 0.f};
  #pragma unroll
  for (int s = 0; s < 4; ++s)
    #pragma unroll
    for (int t = 0; t < 4; ++t)
      acc[t] = __builtin_amdgcn_mfma_f32_16x16x32_bf16(ah[s], bhv[s][t], acc[t], 0, 0, 0);

  // per-wave partials: C/D layout col(way)=lane&15, row(q)=kgrp*4+r (validated)
  #pragma unroll
  for (int t = 0; t < 4; ++t)
    #pragma unroll
    for (int r = 0; r < 4; ++r)
      Sp[wv][kgrp * 4 + r][t * 16 + lrow] = acc[t][r];
  __syncthreads();

  // reduce 8 K-slices, apply 2*dot - pnorm
  for (int i = tid; i < QT * N_WAY; i += 512) {
    int q = i >> 6, w = i & 63;
    float s = 0.f;
    #pragma unroll
    for (int v = 0; v < 8; ++v) s += Sp[v][q][w];
    So[q][w] = 2.f * s - pnL[w];
  }
  __syncthreads();

  // fused log-softmax + argmax: wave 0, 64 lanes = 16 q x 4 way-quarters
  if (tid < 64) {
    const int q = lane & 15;
    const int wq = lane >> 4;
    const int label = qb >> 6;
    float m = -INFINITY; int arg = 0;
    #pragma unroll
    for (int i = 0; i < 16; ++i) {
      int w = wq * 16 + i;
      float v = So[q][w];
      if (v > m) { m = v; arg = w; }
    }
    #pragma unroll
    for (int off = 16; off < 64; off <<= 1) {
      float om = __shfl_xor(m, off);
      int oa = __shfl_xor(arg, off);
      if (om > m || (om == m && oa < arg)) { m = om; arg = oa; }
    }
    float sum = 0.f;
    #pragma unroll
    for (int i = 0; i < 16; ++i) sum += expf(So[q][wq * 16 + i] - m);
    sum += __shfl_xor(sum, 16);
    sum += __shfl_xor(sum, 32);

    float lossq = 0.f, corr = 0.f;
    if (lane < 16) {
      lossq = m + logf(sum) - So[q][label];
      corr = (arg == label) ? 1.f : 0.f;
    }
    #pragma unroll
    for (int off = 8; off > 0; off >>= 1) {
      lossq += __shfl_down(lossq, off);
      corr  += __shfl_down(corr, off);
    }

    // ---- publish + tree arrival (finalizer block is polling the root) ----
    if (lane == 0) {
      __hip_atomic_store(&part[2 * blk],     lossq, __ATOMIC_RELAXED,
                         __HIP_MEMORY_SCOPE_AGENT);
      __hip_atomic_store(&part[2 * blk + 1], corr,  __ATOMIC_RELAXED,
                         __HIP_MEMORY_SCOPE_AGENT);
      asm volatile("s_waitcnt vmcnt(0)" ::: "memory");  // publishes reach LLC
      unsigned leaf = (unsigned)(blk & (NLEAF - 1));
      unsigned ol = __hip_atomic_fetch_add(&ctrs[leaf * CTR_STRIDE], 1u,
                                           __ATOMIC_RELAXED,
                                           __HIP_MEMORY_SCOPE_AGENT);
      if (ol == (GEMM_BLOCKS / NLEAF) - 1)   // leaf-last (8th of this leaf)
        __hip_atomic_fetch_add(&ctrs[NLEAF * CTR_STRIDE], 1u,
                               __ATOMIC_RELAXED, __HIP_MEMORY_SCOPE_AGENT);
    }
  }
}

extern "C" void kernel_launch(void* const* d_in, const int* in_sizes, int n_in,
                              void* d_out, int out_size, void* d_ws, size_t ws_size,
                              hipStream_t stream) {
  (void)in_sizes; (void)n_in; (void)out_size; (void)ws_size;
  const float* x = (const float*)d_in[0];
  float* out = (float*)d_out;

  unsigned short* phi = (unsigned short*)d_ws;        // 64*1024 u16 packed
  float* pnorm4 = (float*)(phi + N_WAY * DIM);        // 256 f32
  float* part   = pnorm4 + 256;                       // 512 f32
  unsigned* ctrs = (unsigned*)(part + 2 * GEMM_BLOCKS); // 33 x 128B-strided u32

  hipLaunchKernelGGL(proto_kernel, dim3(256), dim3(256), 0, stream,
                     x, phi, pnorm4, ctrs);
  hipLaunchKernelGGL(gemm_kernel, dim3(GEMM_BLOCKS + 1), dim3(512), 0, stream,
                     x, phi, pnorm4, part, ctrs, out);
}